// Round 7
// baseline (618.929 us; speedup 1.0000x reference)
//
#include <hip/hip_runtime.h>
#include <hip/hip_bf16.h>

typedef __attribute__((ext_vector_type(8))) __bf16 bf16x8;
typedef __attribute__((ext_vector_type(4))) float f32x4;
typedef unsigned short u16;
typedef unsigned int u32;

constexpr int Nn = 100000;
constexpr int Ee = 1600000;
constexpr int Hd = 128;          // F == H == 128
constexpr int Ll = 4;
constexpr int Gg = 512;
constexpr int Oo = 10;
constexpr int Din = Hd + Ll * Hd; // 640
constexpr int SPLIT = 8;
constexpr int NBLK = (Nn + 127) / 128; // 782 MLP tiles
constexpr int AGG_BLKS = 2048;         // persistent agg grid (8192 waves)

// ---- bucketed CSR build params ----
constexpr int NB = 256;               // buckets
constexpr int NPB = 392;              // nodes per bucket (256*392 = 100352 >= Nn)
constexpr int BCAP = 8192;            // bucket capacity (avg 6250)
constexpr int BATCH = 8192;           // edges per binA block
constexpr int NBATCH = (Ee + BATCH - 1) / BATCH; // 196
constexpr int XCVT_BLKS = Nn * Hd / 8 / 256;     // 6250
constexpr int WPREP_BLKS = Ll * 2 * Hd * Hd / 256; // 512

__device__ __forceinline__ int swzb(int row, int bc) {
  // byte offset into a 128x128 bf16 tile (256 B/row), XOR-swizzled (T2, st-style)
  return (row << 8) + (bc ^ ((row & 7) << 4));
}

__device__ __forceinline__ u16 f2bf(float f) {
  __hip_bfloat16 b = __float2bfloat16(f);
  u16 u;
  __builtin_memcpy(&u, &b, 2);
  return u;
}

__device__ __forceinline__ float bf2f(u32 u) { return __uint_as_float(u << 16); }

__device__ __forceinline__ int lower_bound_dev(const int* a, int n, int key) {
  int lo = 0, hi = n;
  while (lo < hi) { int mid = (lo + hi) >> 1; if (a[mid] < key) lo = mid + 1; else hi = mid; }
  return lo;
}

// async global -> LDS, 16 B per lane (dest = wave-uniform base + lane*16)
__device__ __forceinline__ void gload_lds16(const void* g, void* l) {
  __builtin_amdgcn_global_load_lds((const __attribute__((address_space(1))) unsigned int*)g,
                                   (__attribute__((address_space(3))) unsigned int*)l, 16, 0, 0);
}

// ---- merged prep: xcvt | wprep | (initss + initgptr) ----
__global__ __launch_bounds__(256) void prep_kernel(const float* __restrict__ x, __hip_bfloat16* __restrict__ xb,
                                                   const float* __restrict__ W1s, const float* __restrict__ W2s,
                                                   __hip_bfloat16* __restrict__ wt,
                                                   float* __restrict__ ssbuf, int* __restrict__ gptr) {
  int b = blockIdx.x;
  int tid = threadIdx.x;
  if (b < XCVT_BLKS) {
    int i = b * 256 + tid; // unit of 8 elements
    f32x4 v0 = *(const f32x4*)(x + (size_t)i * 8);
    f32x4 v1 = *(const f32x4*)(x + (size_t)i * 8 + 4);
    uint4 o;
    o.x = (u32)f2bf(v0[0]) | ((u32)f2bf(v0[1]) << 16);
    o.y = (u32)f2bf(v0[2]) | ((u32)f2bf(v0[3]) << 16);
    o.z = (u32)f2bf(v1[0]) | ((u32)f2bf(v1[1]) << 16);
    o.w = (u32)f2bf(v1[2]) | ((u32)f2bf(v1[3]) << 16);
    *(uint4*)((u16*)xb + (size_t)i * 8) = o;
  } else if (b < XCVT_BLKS + WPREP_BLKS) {
    int idx = (b - XCVT_BLKS) * 256 + tid;
    int l = idx >> 15;
    int w = (idx >> 14) & 1;
    int nn = (idx >> 7) & 127;
    int k = idx & 127;
    const float* W = w ? W2s : W1s;
    wt[idx] = __float2bfloat16(W[l * Hd * Hd + k * Hd + nn]);
  } else {
    if (tid < 128) { ssbuf[tid] = 1.f; ssbuf[Hd + tid] = 0.f; } // identity BN for layer-0 input
    gptr[tid] = tid * BCAP;
  }
}

// Phase A: bin edges by dst-bucket with LDS reorder so global writes are coalesced
__global__ __launch_bounds__(256) void binA_kernel(const int* __restrict__ src, const int* __restrict__ dst,
                                                   int* __restrict__ gptr, u32* __restrict__ buckets) {
  __shared__ int hist[NB];
  __shared__ int lbase[NB];
  __shared__ int lpos[NB];
  __shared__ int gbaseS[NB];
  __shared__ int scanT[NB];
  __shared__ u32 reorder[BATCH];
  const int tid = threadIdx.x;
  const int e0 = blockIdx.x * BATCH;
  const int n = min(BATCH, Ee - e0);

  hist[tid] = 0;
  __syncthreads();
  for (int k = tid; k < n; k += 256) {
    int d = dst[e0 + k];
    atomicAdd(&hist[d / NPB], 1);
  }
  __syncthreads();
  int v = hist[tid];
  scanT[tid] = v;
  __syncthreads();
  for (int off = 1; off < NB; off <<= 1) {
    int x = (tid >= off) ? scanT[tid - off] : 0;
    __syncthreads();
    scanT[tid] += x;
    __syncthreads();
  }
  lbase[tid] = scanT[tid] - v;
  lpos[tid] = 0;
  __syncthreads();
  for (int k = tid; k < n; k += 256) {
    int d = dst[e0 + k];
    int s = src[e0 + k];
    int b = d / NPB;
    int dlo = d - b * NPB;
    int p = lbase[b] + atomicAdd(&lpos[b], 1);
    reorder[p] = ((u32)dlo << 17) | (u32)s;
  }
  __syncthreads();
  if (hist[tid] > 0) gbaseS[tid] = atomicAdd(&gptr[tid], hist[tid]);
  __syncthreads();
  for (int p = tid; p < n; p += 256) {
    int lo = 0, hi = NB - 1;
    while (lo < hi) { int mid = (lo + hi + 1) >> 1; if (lbase[mid] <= p) lo = mid; else hi = mid - 1; }
    buckets[gbaseS[lo] + (p - lbase[lo])] = reorder[p];
  }
}

// tiny scan over bucket counts -> adj bases; also terminator of indptr
__global__ __launch_bounds__(256) void bucketscan_kernel(const int* __restrict__ gptr,
                                                         int* __restrict__ bmeta,
                                                         int* __restrict__ indptr) {
  __shared__ int sc[NB];
  int tid = threadIdx.x;
  int cnt = gptr[tid] - tid * BCAP;
  sc[tid] = cnt;
  __syncthreads();
  for (int off = 1; off < NB; off <<= 1) {
    int x = (tid >= off) ? sc[tid - off] : 0;
    __syncthreads();
    sc[tid] += x;
    __syncthreads();
  }
  bmeta[tid] = cnt;
  bmeta[NB + tid] = sc[tid] - cnt; // exclusive = adj base
  if (tid == 0) indptr[Nn] = Ee;
}

// Phase B: per-bucket node histogram + placement (block-local scatter window)
__global__ __launch_bounds__(512) void place_kernel(const u32* __restrict__ buckets,
                                                    const int* __restrict__ bmeta,
                                                    int* __restrict__ indptr, int* __restrict__ adj) {
  __shared__ int ncnt[512];
  __shared__ int nofs[NPB];
  __shared__ int lcur[NPB];
  const int tid = threadIdx.x;
  const int b = blockIdx.x;
  const int cnt = bmeta[b];
  const int adjbase = bmeta[NB + b];
  const int ebase = b * BCAP;
  const int node0 = b * NPB;
  const int nnodes = min(NPB, Nn - node0);

  ncnt[tid] = 0;
  if (tid < NPB) lcur[tid] = 0;
  __syncthreads();
  for (int k = tid; k < cnt; k += 512) atomicAdd(&ncnt[buckets[ebase + k] >> 17], 1);
  __syncthreads();
  int v = ncnt[tid];
  for (int off = 1; off < 512; off <<= 1) {
    int x = (tid >= off) ? ncnt[tid - off] : 0;
    __syncthreads();
    ncnt[tid] += x;
    __syncthreads();
  }
  if (tid < NPB) nofs[tid] = ncnt[tid] - v;
  __syncthreads();
  if (tid < nnodes) indptr[node0 + tid] = adjbase + nofs[tid];
  for (int k = tid; k < cnt; k += 512) {
    u32 u = buckets[ebase + k];
    int dlo = u >> 17;
    int s = (int)(u & 0x1FFFFu);
    int p = atomicAdd(&lcur[dlo], 1);
    adj[adjbase + nofs[dlo] + p] = s;
  }
}

// ---- aggregation with lazy BN: t = bf16((1+eps)*h_self + sum h_nbr),
//      h = max(z*sc+sh, negLim). Persistent grid-stride: one wave per node per step.
__global__ __launch_bounds__(256) void agg_kernel(const __hip_bfloat16* __restrict__ zprev,
                                                  const int* __restrict__ indptr,
                                                  const int* __restrict__ adj,
                                                  const float* __restrict__ ssin,
                                                  const float* __restrict__ epsp,
                                                  int layer, float negLim,
                                                  __hip_bfloat16* __restrict__ t) {
  const int gwave = blockIdx.x * 4 + (threadIdx.x >> 6);
  const int nwaves = AGG_BLKS * 4;
  const int lane = threadIdx.x & 63;
  const int cb = lane * 2; // feature pair base
  const u16* zp = (const u16*)zprev;
  const float sc0 = ssin[cb], sh0 = ssin[Hd + cb];
  const float sc1 = ssin[cb + 1], sh1 = ssin[Hd + cb + 1];
  const float eps1 = 1.0f + epsp[layer];

  for (int node = gwave; node < Nn; node += nwaves) {
    int s = __builtin_amdgcn_readfirstlane(indptr[node]);
    int e = __builtin_amdgcn_readfirstlane(indptr[node + 1]);
    float a0 = 0.f, a1 = 0.f;
    int p = s;
    while (p + 16 <= e) {
      u32 v[16];
      #pragma unroll
      for (int j = 0; j < 16; ++j) v[j] = *(const u32*)(zp + (size_t)adj[p + j] * Hd + cb);
      #pragma unroll
      for (int j = 0; j < 16; ++j) {
        a0 += fmaxf(fmaf(bf2f(v[j] & 0xffffu), sc0, sh0), negLim);
        a1 += fmaxf(fmaf(bf2f(v[j] >> 16), sc1, sh1), negLim);
      }
      p += 16;
    }
    if (p + 8 <= e) {
      u32 v[8];
      #pragma unroll
      for (int j = 0; j < 8; ++j) v[j] = *(const u32*)(zp + (size_t)adj[p + j] * Hd + cb);
      #pragma unroll
      for (int j = 0; j < 8; ++j) {
        a0 += fmaxf(fmaf(bf2f(v[j] & 0xffffu), sc0, sh0), negLim);
        a1 += fmaxf(fmaf(bf2f(v[j] >> 16), sc1, sh1), negLim);
      }
      p += 8;
    }
    if (p + 4 <= e) {
      u32 v[4];
      #pragma unroll
      for (int j = 0; j < 4; ++j) v[j] = *(const u32*)(zp + (size_t)adj[p + j] * Hd + cb);
      #pragma unroll
      for (int j = 0; j < 4; ++j) {
        a0 += fmaxf(fmaf(bf2f(v[j] & 0xffffu), sc0, sh0), negLim);
        a1 += fmaxf(fmaf(bf2f(v[j] >> 16), sc1, sh1), negLim);
      }
      p += 4;
    }
    for (; p < e; ++p) {
      u32 v0 = *(const u32*)(zp + (size_t)adj[p] * Hd + cb);
      a0 += fmaxf(fmaf(bf2f(v0 & 0xffffu), sc0, sh0), negLim);
      a1 += fmaxf(fmaf(bf2f(v0 >> 16), sc1, sh1), negLim);
    }
    u32 sv = *(const u32*)(zp + (size_t)node * Hd + cb);
    float s0 = fmaxf(fmaf(bf2f(sv & 0xffffu), sc0, sh0), negLim);
    float s1 = fmaxf(fmaf(bf2f(sv >> 16), sc1, sh1), negLim);
    float t0 = eps1 * s0 + a0;
    float t1 = eps1 * s1 + a1;
    *(u32*)((u16*)t + (size_t)node * Hd + cb) = (u32)f2bf(t0) | ((u32)f2bf(t1) << 16);
  }
}

// ---- fused 2-GEMM MLP + BN partial stats: z = relu(t@W1+b1)@W2 + b2 ----
// A staged via global_load_lds (pre-swizzled source, linear LDS dest);
// W fragments read directly from L2 (64 KB shared by all blocks) -> LDS = 32 KB.
__global__ __launch_bounds__(256) void mlp_kernel(const __hip_bfloat16* __restrict__ t,
                                                  const __hip_bfloat16* __restrict__ w1t,
                                                  const __hip_bfloat16* __restrict__ w2t,
                                                  const float* __restrict__ b1,
                                                  const float* __restrict__ b2,
                                                  __hip_bfloat16* __restrict__ z,
                                                  float* __restrict__ pstats) {
  __shared__ __align__(16) unsigned char sA[32 * 1024]; // A tile, then U tile, then stats red
  const int tid = threadIdx.x;
  const int m0 = blockIdx.x * 128;
  const int lane = tid & 63;
  const int wave = tid >> 6;

  // stage A: each wave fills 8 contiguous 1KB groups (pre-swizzled global source)
  #pragma unroll
  for (int blk = 0; blk < 8; ++blk) {
    const int chunk = wave * 512 + blk * 64 + lane;
    const int row = chunk >> 4, pos = chunk & 15;
    const int spos = pos ^ (row & 7);
    // rows past Nn read garbage (readable ws); their outputs are discarded below
    gload_lds16((const unsigned char*)t + (size_t)(m0 + row) * 256 + spos * 16,
                sA + (size_t)(wave * 512 + blk * 64) * 16);
  }
  __syncthreads();

  const int lrow = lane & 15;
  const int lkb = (lane >> 4) << 4;   // byte offset of this lane's k-octet
  const int wm = wave * 32;           // wave's 32 output rows
  const int crow = (lane >> 4) << 2;  // C/D row base

  f32x4 acc[2][8];
  #pragma unroll
  for (int a = 0; a < 2; ++a) {
    #pragma unroll
    for (int b = 0; b < 8; ++b) acc[a][b] = (f32x4){0.f, 0.f, 0.f, 0.f};
  }

  #pragma unroll
  for (int kk = 0; kk < 4; ++kk) {
    const int kb2 = kk * 64 + lkb;
    bf16x8 a0 = *(const bf16x8*)(sA + swzb(wm + lrow, kb2));
    bf16x8 a1 = *(const bf16x8*)(sA + swzb(wm + 16 + lrow, kb2));
    #pragma unroll
    for (int nf = 0; nf < 8; ++nf) {
      bf16x8 bfr = *(const bf16x8*)((const unsigned char*)w1t + (nf * 16 + lrow) * 256 + kb2);
      acc[0][nf] = __builtin_amdgcn_mfma_f32_16x16x32_bf16(a0, bfr, acc[0][nf], 0, 0, 0);
      acc[1][nf] = __builtin_amdgcn_mfma_f32_16x16x32_bf16(a1, bfr, acc[1][nf], 0, 0, 0);
    }
  }
  __syncthreads(); // all reads of A done before overwrite with U

  // write U = bf16(relu(acc + b1)) into sA (same swizzle)
  #pragma unroll
  for (int nf = 0; nf < 8; ++nf) {
    const int col = nf * 16 + lrow;
    const float bb = b1[col];
    #pragma unroll
    for (int mf = 0; mf < 2; ++mf) {
      #pragma unroll
      for (int j = 0; j < 4; ++j) {
        float v = acc[mf][nf][j] + bb;
        v = v > 0.f ? v : 0.f;
        int row = wm + mf * 16 + crow + j;
        *(u16*)(sA + swzb(row, col * 2)) = f2bf(v);
      }
    }
  }
  __syncthreads();

  f32x4 acc2[2][8];
  #pragma unroll
  for (int a = 0; a < 2; ++a) {
    #pragma unroll
    for (int b = 0; b < 8; ++b) acc2[a][b] = (f32x4){0.f, 0.f, 0.f, 0.f};
  }
  #pragma unroll
  for (int kk = 0; kk < 4; ++kk) {
    const int kb2 = kk * 64 + lkb;
    bf16x8 a0 = *(const bf16x8*)(sA + swzb(wm + lrow, kb2));
    bf16x8 a1 = *(const bf16x8*)(sA + swzb(wm + 16 + lrow, kb2));
    #pragma unroll
    for (int nf = 0; nf < 8; ++nf) {
      bf16x8 bfr = *(const bf16x8*)((const unsigned char*)w2t + (nf * 16 + lrow) * 256 + kb2);
      acc2[0][nf] = __builtin_amdgcn_mfma_f32_16x16x32_bf16(a0, bfr, acc2[0][nf], 0, 0, 0);
      acc2[1][nf] = __builtin_amdgcn_mfma_f32_16x16x32_bf16(a1, bfr, acc2[1][nf], 0, 0, 0);
    }
  }
  __syncthreads(); // done reading sA; reuse for stats reduce

  float* sred = (float*)sA;          // [4][128]
  float* qred = (float*)(sA + 2048); // [4][128]
  u16* zp = (u16*)z;
  #pragma unroll
  for (int nf = 0; nf < 8; ++nf) {
    const int col = nf * 16 + lrow;
    const float bb = b2[col];
    float s = 0.f, q = 0.f;
    #pragma unroll
    for (int mf = 0; mf < 2; ++mf) {
      #pragma unroll
      for (int j = 0; j < 4; ++j) {
        int grow = m0 + wm + mf * 16 + crow + j;
        if (grow < Nn) {
          float v = acc2[mf][nf][j] + bb;
          zp[(size_t)grow * Hd + col] = f2bf(v);
          s += v; q += v * v;
        }
      }
    }
    s += __shfl_xor(s, 16, 64); s += __shfl_xor(s, 32, 64);
    q += __shfl_xor(q, 16, 64); q += __shfl_xor(q, 32, 64);
    if (lane < 16) { sred[wave * 128 + col] = s; qred[wave * 128 + col] = q; }
  }
  __syncthreads();
  if (tid < 128) {
    float a = sred[tid] + sred[128 + tid] + sred[256 + tid] + sred[384 + tid];
    pstats[(size_t)blockIdx.x * 256 + tid] = a;
  } else {
    int c = tid - 128;
    float a = qred[c] + qred[128 + c] + qred[256 + c] + qred[384 + c];
    pstats[(size_t)blockIdx.x * 256 + tid] = a;
  }
}

// ---- fused stats reduce + BN param: one block per feature ----
__global__ __launch_bounds__(256) void stats_bn_kernel(const float* __restrict__ pstats,
                                                       const float* __restrict__ gammas,
                                                       const float* __restrict__ betas,
                                                       int layer, float* __restrict__ ss) {
  __shared__ float reds[256];
  __shared__ float redq[256];
  int f = blockIdx.x; // 0..127
  int t = threadIdx.x;
  float s = 0.f, q = 0.f;
  for (int i = t; i < NBLK; i += 256) {
    s += pstats[(size_t)i * 256 + f];
    q += pstats[(size_t)i * 256 + 128 + f];
  }
  reds[t] = s; redq[t] = q;
  __syncthreads();
  for (int o = 128; o > 0; o >>= 1) {
    if (t < o) { reds[t] += reds[t + o]; redq[t] += redq[t + o]; }
    __syncthreads();
  }
  if (t == 0) {
    const float invn = 1.0f / (float)Nn;
    float mu = reds[0] * invn;
    float var = redq[0] * invn - mu * mu;
    float sc = gammas[layer * Hd + f] * rsqrtf(var + 1e-5f);
    ss[f] = sc;
    ss[Hd + f] = betas[layer * Hd + f] - mu * sc;
  }
}

// ---- one pooling kernel for all 5 sources: emb[g, colOff+f] += sum max(z*sc+sh, negLim) ----
__global__ __launch_bounds__(128) void pool_all_kernel(const __hip_bfloat16* __restrict__ xb,
                                                       const __hip_bfloat16* __restrict__ z0,
                                                       const __hip_bfloat16* __restrict__ z1,
                                                       const __hip_bfloat16* __restrict__ z2,
                                                       const __hip_bfloat16* __restrict__ z3,
                                                       const float* __restrict__ ssbuf,
                                                       const int* __restrict__ batch,
                                                       float* __restrict__ emb) {
  const int b = blockIdx.x;
  const int s = b / (Gg * SPLIT);
  const int rem = b % (Gg * SPLIT);
  const int g = rem / SPLIT, sp = rem % SPLIT;
  const __hip_bfloat16* zsrc = (s == 0) ? xb : (s == 1) ? z0 : (s == 2) ? z1 : (s == 3) ? z2 : z3;
  const float* ss = ssbuf + (size_t)s * 256;
  const float negLim = (s == 0) ? -3.4e38f : 0.f;
  const int colOff = s * Hd;
  const int c2 = (threadIdx.x & 63) * 2;
  const int rh = threadIdx.x >> 6;
  const float sc0 = ss[c2], sh0 = ss[Hd + c2];
  const float sc1 = ss[c2 + 1], sh1 = ss[Hd + c2 + 1];
  int lo = lower_bound_dev(batch, Nn, g);
  int hi = lower_bound_dev(batch, Nn, g + 1);
  int len = hi - lo;
  if (len <= 0) return;
  int chunk = (len + SPLIT - 1) / SPLIT;
  int rs = lo + sp * chunk;
  int re = min(rs + chunk, hi);
  if (rs >= re) return;
  const u16* zp = (const u16*)zsrc;
  float a0 = 0.f, a1 = 0.f;
  for (int i = rs + rh; i < re; i += 2) {
    u32 v = *(const u32*)(zp + (size_t)i * Hd + c2);
    a0 += fmaxf(fmaf(bf2f(v & 0xffffu), sc0, sh0), negLim);
    a1 += fmaxf(fmaf(bf2f(v >> 16), sc1, sh1), negLim);
  }
  atomicAdd(&emb[g * Din + colOff + c2], a0);
  atomicAdd(&emb[g * Din + colOff + c2 + 1], a1);
}

// ---- output head: out = emb @ Wout + bout ----
__global__ __launch_bounds__(64) void out_kernel(const float* __restrict__ emb, const float* __restrict__ Wout,
                                                 const float* __restrict__ bout, float* __restrict__ out) {
  int g = blockIdx.x;
  int lane = threadIdx.x;
  float acc[Oo];
  #pragma unroll
  for (int o = 0; o < Oo; ++o) acc[o] = 0.f;
  for (int d = lane; d < Din; d += 64) {
    float ev = emb[g * Din + d];
    #pragma unroll
    for (int o = 0; o < Oo; ++o) acc[o] += ev * Wout[d * Oo + o];
  }
  #pragma unroll
  for (int off = 32; off > 0; off >>= 1) {
    #pragma unroll
    for (int o = 0; o < Oo; ++o) acc[o] += __shfl_down(acc[o], off, 64);
  }
  if (lane == 0) {
    #pragma unroll
    for (int o = 0; o < Oo; ++o) out[g * Oo + o] = acc[o] + bout[o];
  }
}

extern "C" void kernel_launch(void* const* d_in, const int* in_sizes, int n_in,
                              void* d_out, int out_size, void* d_ws, size_t ws_size,
                              hipStream_t stream) {
  (void)in_sizes; (void)n_in; (void)out_size;
  const float* x = (const float*)d_in[0];
  const int* ei = (const int*)d_in[1];
  const int* src = ei;
  const int* dst = ei + Ee;
  const int* batch = (const int*)d_in[2];
  const float* W1s = (const float*)d_in[3];
  const float* b1s = (const float*)d_in[4];
  const float* W2s = (const float*)d_in[5];
  const float* b2s = (const float*)d_in[6];
  const float* eps = (const float*)d_in[7];
  const float* gammas = (const float*)d_in[8];
  const float* betas = (const float*)d_in[9];
  const float* Wout = (const float*)d_in[10];
  const float* bout = (const float*)d_in[11];
  float* out = (float*)d_out;

  unsigned char* ws = (unsigned char*)d_ws;
  size_t off = 0;
  auto alloc = [&](size_t bytes) -> void* {
    void* p = ws + off;
    off = (off + bytes + 255) & ~size_t(255);
    return p;
  };
  __hip_bfloat16* xb = (__hip_bfloat16*)alloc((size_t)Nn * Hd * 2);
  __hip_bfloat16* z[Ll];
  for (int l = 0; l < Ll; ++l) z[l] = (__hip_bfloat16*)alloc((size_t)Nn * Hd * 2);
  __hip_bfloat16* t = (__hip_bfloat16*)alloc((size_t)Nn * Hd * 2);
  int* indptr = (int*)alloc((size_t)(Nn + 1) * 4);  // readable pad after t (OOB tile rows)
  int* adj = (int*)alloc((size_t)Ee * 4);
  u32* buckets = (u32*)alloc((size_t)NB * BCAP * 4);
  int* gptr = (int*)alloc((size_t)NB * 4);
  int* bmeta = (int*)alloc((size_t)2 * NB * 4);
  float* emb = (float*)alloc((size_t)Gg * Din * 4);
  float* pstats = (float*)alloc((size_t)NBLK * 256 * 4);
  float* ssbuf = (float*)alloc((size_t)(Ll + 1) * 256 * 4);
  __hip_bfloat16* wt = (__hip_bfloat16*)alloc((size_t)Ll * 2 * Hd * Hd * 2);
  if (off > ws_size) return; // workspace too small -> leave output poisoned (visible failure)

  hipMemsetAsync(emb, 0, (size_t)Gg * Din * 4, stream);

  prep_kernel<<<XCVT_BLKS + WPREP_BLKS + 1, 256, 0, stream>>>(x, xb, W1s, W2s, wt, ssbuf, gptr);

  // bucketed CSR build
  binA_kernel<<<NBATCH, 256, 0, stream>>>(src, dst, gptr, buckets);
  bucketscan_kernel<<<1, NB, 0, stream>>>(gptr, bmeta, indptr);
  place_kernel<<<NB, 512, 0, stream>>>(buckets, bmeta, indptr, adj);

  const __hip_bfloat16* zprev = xb;
  for (int l = 0; l < Ll; ++l) {
    float negLim = (l == 0) ? -3.4e38f : 0.f;
    agg_kernel<<<AGG_BLKS, 256, 0, stream>>>(zprev, indptr, adj, ssbuf + (size_t)l * 256,
                                             eps, l, negLim, t);
    mlp_kernel<<<NBLK, 256, 0, stream>>>(
        t, wt + (size_t)l * 2 * Hd * Hd, wt + (size_t)l * 2 * Hd * Hd + Hd * Hd,
        b1s + l * Hd, b2s + l * Hd, z[l], pstats);
    stats_bn_kernel<<<128, 256, 0, stream>>>(pstats, gammas, betas, l, ssbuf + (size_t)(l + 1) * 256);
    zprev = z[l];
  }

  pool_all_kernel<<<5 * Gg * SPLIT, 128, 0, stream>>>(xb, z[0], z[1], z[2], z[3],
                                                      ssbuf, batch, emb);

  out_kernel<<<Gg, 64, 0, stream>>>(emb, Wout, bout, out);
}

// Round 8
// 511.172 us; speedup vs baseline: 1.2108x; 1.2108x over previous
//
#include <hip/hip_runtime.h>
#include <hip/hip_bf16.h>

typedef __attribute__((ext_vector_type(8))) __bf16 bf16x8;
typedef __attribute__((ext_vector_type(4))) float f32x4;
typedef unsigned short u16;
typedef unsigned int u32;

constexpr int Nn = 100000;
constexpr int Ee = 1600000;
constexpr int Hd = 128;          // F == H == 128
constexpr int Ll = 4;
constexpr int Gg = 512;
constexpr int Oo = 10;
constexpr int Din = Hd + Ll * Hd; // 640
constexpr int PSPLIT = 4;
constexpr int NBLK = (Nn + 127) / 128; // 782 MLP tiles
constexpr int AGG_BLKS = 2048;         // persistent agg grid (8192 waves)

// ---- bucketed CSR build params ----
constexpr int NB = 256;               // buckets
constexpr int NPB = 392;              // nodes per bucket (256*392 = 100352 >= Nn)
constexpr int BCAP = 8192;            // bucket capacity (avg 6250)
constexpr int BATCH = 8192;           // edges per binA block
constexpr int NBATCH = (Ee + BATCH - 1) / BATCH; // 196
constexpr int XCVT_BLKS = Nn * Hd / 8 / 256;     // 6250
constexpr int WPREP_BLKS = Ll * 2 * Hd * Hd / 256; // 512

__device__ __forceinline__ int swzb(int row, int bc) {
  // byte offset into a 128x128 bf16 tile (256 B/row), XOR-swizzled (T2, st-style)
  return (row << 8) + (bc ^ ((row & 7) << 4));
}

__device__ __forceinline__ u16 f2bf(float f) {
  __hip_bfloat16 b = __float2bfloat16(f);
  u16 u;
  __builtin_memcpy(&u, &b, 2);
  return u;
}

__device__ __forceinline__ float bf2f(u32 u) { return __uint_as_float(u << 16); }

__device__ __forceinline__ int lower_bound_dev(const int* a, int n, int key) {
  int lo = 0, hi = n;
  while (lo < hi) { int mid = (lo + hi) >> 1; if (a[mid] < key) lo = mid + 1; else hi = mid; }
  return lo;
}

// async global -> LDS, 16 B per lane (dest = wave-uniform base + lane*16)
__device__ __forceinline__ void gload_lds16(const void* g, void* l) {
  __builtin_amdgcn_global_load_lds((const __attribute__((address_space(1))) unsigned int*)g,
                                   (__attribute__((address_space(3))) unsigned int*)l, 16, 0, 0);
}

// ---- merged prep: xcvt | wprep | (initss + initgptr + graph bounds) ----
__global__ __launch_bounds__(256) void prep_kernel(const float* __restrict__ x, __hip_bfloat16* __restrict__ xb,
                                                   const float* __restrict__ W1s, const float* __restrict__ W2s,
                                                   __hip_bfloat16* __restrict__ wt,
                                                   float* __restrict__ ssbuf, int* __restrict__ gptr,
                                                   const int* __restrict__ batch, int* __restrict__ gb) {
  int b = blockIdx.x;
  int tid = threadIdx.x;
  if (b < XCVT_BLKS) {
    int i = b * 256 + tid; // unit of 8 elements
    f32x4 v0 = *(const f32x4*)(x + (size_t)i * 8);
    f32x4 v1 = *(const f32x4*)(x + (size_t)i * 8 + 4);
    uint4 o;
    o.x = (u32)f2bf(v0[0]) | ((u32)f2bf(v0[1]) << 16);
    o.y = (u32)f2bf(v0[2]) | ((u32)f2bf(v0[3]) << 16);
    o.z = (u32)f2bf(v1[0]) | ((u32)f2bf(v1[1]) << 16);
    o.w = (u32)f2bf(v1[2]) | ((u32)f2bf(v1[3]) << 16);
    *(uint4*)((u16*)xb + (size_t)i * 8) = o;
  } else if (b < XCVT_BLKS + WPREP_BLKS) {
    int idx = (b - XCVT_BLKS) * 256 + tid;
    int l = idx >> 15;
    int w = (idx >> 14) & 1;
    int nn = (idx >> 7) & 127;
    int k = idx & 127;
    const float* W = w ? W2s : W1s;
    wt[idx] = __float2bfloat16(W[l * Hd * Hd + k * Hd + nn]);
  } else {
    if (tid < 128) { ssbuf[tid] = 1.f; ssbuf[Hd + tid] = 0.f; } // identity BN for layer-0 input
    gptr[tid] = tid * BCAP;
    for (int g = tid; g <= Gg; g += 256)
      gb[g] = (g == Gg) ? Nn : lower_bound_dev(batch, Nn, g);
  }
}

// Phase A: bin edges by dst-bucket with LDS reorder so global writes are coalesced
__global__ __launch_bounds__(256) void binA_kernel(const int* __restrict__ src, const int* __restrict__ dst,
                                                   int* __restrict__ gptr, u32* __restrict__ buckets) {
  __shared__ int hist[NB];
  __shared__ int lbase[NB];
  __shared__ int lpos[NB];
  __shared__ int gbaseS[NB];
  __shared__ int scanT[NB];
  __shared__ u32 reorder[BATCH];
  const int tid = threadIdx.x;
  const int e0 = blockIdx.x * BATCH;
  const int n = min(BATCH, Ee - e0);

  hist[tid] = 0;
  __syncthreads();
  for (int k = tid; k < n; k += 256) {
    int d = dst[e0 + k];
    atomicAdd(&hist[d / NPB], 1);
  }
  __syncthreads();
  int v = hist[tid];
  scanT[tid] = v;
  __syncthreads();
  for (int off = 1; off < NB; off <<= 1) {
    int x = (tid >= off) ? scanT[tid - off] : 0;
    __syncthreads();
    scanT[tid] += x;
    __syncthreads();
  }
  lbase[tid] = scanT[tid] - v;
  lpos[tid] = 0;
  __syncthreads();
  for (int k = tid; k < n; k += 256) {
    int d = dst[e0 + k];
    int s = src[e0 + k];
    int b = d / NPB;
    int dlo = d - b * NPB;
    int p = lbase[b] + atomicAdd(&lpos[b], 1);
    reorder[p] = ((u32)dlo << 17) | (u32)s;
  }
  __syncthreads();
  if (hist[tid] > 0) gbaseS[tid] = atomicAdd(&gptr[tid], hist[tid]);
  __syncthreads();
  for (int p = tid; p < n; p += 256) {
    int lo = 0, hi = NB - 1;
    while (lo < hi) { int mid = (lo + hi + 1) >> 1; if (lbase[mid] <= p) lo = mid; else hi = mid - 1; }
    buckets[gbaseS[lo] + (p - lbase[lo])] = reorder[p];
  }
}

// tiny scan over bucket counts -> adj bases; also terminator of indptr
__global__ __launch_bounds__(256) void bucketscan_kernel(const int* __restrict__ gptr,
                                                         int* __restrict__ bmeta,
                                                         int* __restrict__ indptr) {
  __shared__ int sc[NB];
  int tid = threadIdx.x;
  int cnt = gptr[tid] - tid * BCAP;
  sc[tid] = cnt;
  __syncthreads();
  for (int off = 1; off < NB; off <<= 1) {
    int x = (tid >= off) ? sc[tid - off] : 0;
    __syncthreads();
    sc[tid] += x;
    __syncthreads();
  }
  bmeta[tid] = cnt;
  bmeta[NB + tid] = sc[tid] - cnt; // exclusive = adj base
  if (tid == 0) indptr[Nn] = Ee;
}

// Phase B: per-bucket node histogram + placement (block-local scatter window)
__global__ __launch_bounds__(512) void place_kernel(const u32* __restrict__ buckets,
                                                    const int* __restrict__ bmeta,
                                                    int* __restrict__ indptr, int* __restrict__ adj) {
  __shared__ int ncnt[512];
  __shared__ int nofs[NPB];
  __shared__ int lcur[NPB];
  const int tid = threadIdx.x;
  const int b = blockIdx.x;
  const int cnt = bmeta[b];
  const int adjbase = bmeta[NB + b];
  const int ebase = b * BCAP;
  const int node0 = b * NPB;
  const int nnodes = min(NPB, Nn - node0);

  ncnt[tid] = 0;
  if (tid < NPB) lcur[tid] = 0;
  __syncthreads();
  for (int k = tid; k < cnt; k += 512) atomicAdd(&ncnt[buckets[ebase + k] >> 17], 1);
  __syncthreads();
  int v = ncnt[tid];
  for (int off = 1; off < 512; off <<= 1) {
    int x = (tid >= off) ? ncnt[tid - off] : 0;
    __syncthreads();
    ncnt[tid] += x;
    __syncthreads();
  }
  if (tid < NPB) nofs[tid] = ncnt[tid] - v;
  __syncthreads();
  if (tid < nnodes) indptr[node0 + tid] = adjbase + nofs[tid];
  for (int k = tid; k < cnt; k += 512) {
    u32 u = buckets[ebase + k];
    int dlo = u >> 17;
    int s = (int)(u & 0x1FFFFu);
    int p = atomicAdd(&lcur[dlo], 1);
    adj[adjbase + nofs[dlo] + p] = s;
  }
}

// ---- aggregation with lazy BN: t = bf16((1+eps)*h_self + sum h_nbr),
//      h = max(z*sc+sh, negLim). Persistent grid-stride: one wave per node per step.
__global__ __launch_bounds__(256) void agg_kernel(const __hip_bfloat16* __restrict__ zprev,
                                                  const int* __restrict__ indptr,
                                                  const int* __restrict__ adj,
                                                  const float* __restrict__ ssin,
                                                  const float* __restrict__ epsp,
                                                  int layer, float negLim,
                                                  __hip_bfloat16* __restrict__ t) {
  const int gwave = blockIdx.x * 4 + (threadIdx.x >> 6);
  const int nwaves = AGG_BLKS * 4;
  const int lane = threadIdx.x & 63;
  const int cb = lane * 2; // feature pair base
  const u16* zp = (const u16*)zprev;
  const float sc0 = ssin[cb], sh0 = ssin[Hd + cb];
  const float sc1 = ssin[cb + 1], sh1 = ssin[Hd + cb + 1];
  const float eps1 = 1.0f + epsp[layer];

  for (int node = gwave; node < Nn; node += nwaves) {
    int s = __builtin_amdgcn_readfirstlane(indptr[node]);
    int e = __builtin_amdgcn_readfirstlane(indptr[node + 1]);
    float a0 = 0.f, a1 = 0.f;
    int p = s;
    while (p + 16 <= e) {
      u32 v[16];
      #pragma unroll
      for (int j = 0; j < 16; ++j) v[j] = *(const u32*)(zp + (size_t)adj[p + j] * Hd + cb);
      #pragma unroll
      for (int j = 0; j < 16; ++j) {
        a0 += fmaxf(fmaf(bf2f(v[j] & 0xffffu), sc0, sh0), negLim);
        a1 += fmaxf(fmaf(bf2f(v[j] >> 16), sc1, sh1), negLim);
      }
      p += 16;
    }
    if (p + 8 <= e) {
      u32 v[8];
      #pragma unroll
      for (int j = 0; j < 8; ++j) v[j] = *(const u32*)(zp + (size_t)adj[p + j] * Hd + cb);
      #pragma unroll
      for (int j = 0; j < 8; ++j) {
        a0 += fmaxf(fmaf(bf2f(v[j] & 0xffffu), sc0, sh0), negLim);
        a1 += fmaxf(fmaf(bf2f(v[j] >> 16), sc1, sh1), negLim);
      }
      p += 8;
    }
    if (p + 4 <= e) {
      u32 v[4];
      #pragma unroll
      for (int j = 0; j < 4; ++j) v[j] = *(const u32*)(zp + (size_t)adj[p + j] * Hd + cb);
      #pragma unroll
      for (int j = 0; j < 4; ++j) {
        a0 += fmaxf(fmaf(bf2f(v[j] & 0xffffu), sc0, sh0), negLim);
        a1 += fmaxf(fmaf(bf2f(v[j] >> 16), sc1, sh1), negLim);
      }
      p += 4;
    }
    for (; p < e; ++p) {
      u32 v0 = *(const u32*)(zp + (size_t)adj[p] * Hd + cb);
      a0 += fmaxf(fmaf(bf2f(v0 & 0xffffu), sc0, sh0), negLim);
      a1 += fmaxf(fmaf(bf2f(v0 >> 16), sc1, sh1), negLim);
    }
    u32 sv = *(const u32*)(zp + (size_t)node * Hd + cb);
    float s0 = fmaxf(fmaf(bf2f(sv & 0xffffu), sc0, sh0), negLim);
    float s1 = fmaxf(fmaf(bf2f(sv >> 16), sc1, sh1), negLim);
    float t0 = eps1 * s0 + a0;
    float t1 = eps1 * s1 + a1;
    *(u32*)((u16*)t + (size_t)node * Hd + cb) = (u32)f2bf(t0) | ((u32)f2bf(t1) << 16);
  }
}

// ---- fused 2-GEMM MLP + BN partial stats: z = relu(t@W1+b1)@W2 + b2 ----
// Staging via global_load_lds (16B/lane), pre-swizzled global source so LDS
// content matches the swzb layout (m173 pattern: swizzle source, linear dest).
__global__ __launch_bounds__(256) void mlp_kernel(const __hip_bfloat16* __restrict__ t,
                                                  const __hip_bfloat16* __restrict__ w1t,
                                                  const __hip_bfloat16* __restrict__ w2t,
                                                  const float* __restrict__ b1,
                                                  const float* __restrict__ b2,
                                                  __hip_bfloat16* __restrict__ z,
                                                  float* __restrict__ pstats) {
  __shared__ __align__(16) unsigned char sA[32 * 1024]; // A tile, then U tile
  __shared__ __align__(16) unsigned char sW[32 * 1024]; // W1t, then W2t
  const int tid = threadIdx.x;
  const int m0 = blockIdx.x * 128;
  const int lane = tid & 63;
  const int wave = tid >> 6;

  // stage A + W1t: each wave fills 8 contiguous 64-chunk (1KB) groups
  #pragma unroll
  for (int blk = 0; blk < 8; ++blk) {
    const int chunk = wave * 512 + blk * 64 + lane;
    const int row = chunk >> 4, pos = chunk & 15;
    const int spos = pos ^ (row & 7);
    void* ldst = sA + (size_t)(wave * 512 + blk * 64) * 16;
    void* ldstW = sW + (size_t)(wave * 512 + blk * 64) * 16;
    gload_lds16((const unsigned char*)w1t + row * 256 + spos * 16, ldstW);
    // rows past Nn read garbage (readable ws); their outputs are discarded below
    gload_lds16((const unsigned char*)t + (size_t)(m0 + row) * 256 + spos * 16, ldst);
  }
  __syncthreads();

  const int lrow = lane & 15;
  const int lkb = (lane >> 4) << 4;   // byte offset of this lane's k-octet
  const int wm = wave * 32;           // wave's 32 output rows
  const int crow = (lane >> 4) << 2;  // C/D row base

  f32x4 acc[2][8];
  #pragma unroll
  for (int a = 0; a < 2; ++a) {
    #pragma unroll
    for (int b = 0; b < 8; ++b) acc[a][b] = (f32x4){0.f, 0.f, 0.f, 0.f};
  }

  #pragma unroll
  for (int kk = 0; kk < 4; ++kk) {
    const int kb2 = kk * 64 + lkb;
    bf16x8 a0 = *(const bf16x8*)(sA + swzb(wm + lrow, kb2));
    bf16x8 a1 = *(const bf16x8*)(sA + swzb(wm + 16 + lrow, kb2));
    #pragma unroll
    for (int nf = 0; nf < 8; ++nf) {
      bf16x8 bfr = *(const bf16x8*)(sW + swzb(nf * 16 + lrow, kb2));
      acc[0][nf] = __builtin_amdgcn_mfma_f32_16x16x32_bf16(a0, bfr, acc[0][nf], 0, 0, 0);
      acc[1][nf] = __builtin_amdgcn_mfma_f32_16x16x32_bf16(a1, bfr, acc[1][nf], 0, 0, 0);
    }
  }
  __syncthreads();

  // stage W2t (async, drains at next barrier); write U = bf16(relu(acc+b1)) into sA
  #pragma unroll
  for (int blk = 0; blk < 8; ++blk) {
    const int chunk = wave * 512 + blk * 64 + lane;
    const int row = chunk >> 4, pos = chunk & 15;
    const int spos = pos ^ (row & 7);
    gload_lds16((const unsigned char*)w2t + row * 256 + spos * 16,
                sW + (size_t)(wave * 512 + blk * 64) * 16);
  }
  #pragma unroll
  for (int nf = 0; nf < 8; ++nf) {
    const int col = nf * 16 + lrow;
    const float bb = b1[col];
    #pragma unroll
    for (int mf = 0; mf < 2; ++mf) {
      #pragma unroll
      for (int j = 0; j < 4; ++j) {
        float v = acc[mf][nf][j] + bb;
        v = v > 0.f ? v : 0.f;
        int row = wm + mf * 16 + crow + j;
        *(u16*)(sA + swzb(row, col * 2)) = f2bf(v);
      }
    }
  }
  __syncthreads();

  f32x4 acc2[2][8];
  #pragma unroll
  for (int a = 0; a < 2; ++a) {
    #pragma unroll
    for (int b = 0; b < 8; ++b) acc2[a][b] = (f32x4){0.f, 0.f, 0.f, 0.f};
  }
  #pragma unroll
  for (int kk = 0; kk < 4; ++kk) {
    const int kb2 = kk * 64 + lkb;
    bf16x8 a0 = *(const bf16x8*)(sA + swzb(wm + lrow, kb2));
    bf16x8 a1 = *(const bf16x8*)(sA + swzb(wm + 16 + lrow, kb2));
    #pragma unroll
    for (int nf = 0; nf < 8; ++nf) {
      bf16x8 bfr = *(const bf16x8*)(sW + swzb(nf * 16 + lrow, kb2));
      acc2[0][nf] = __builtin_amdgcn_mfma_f32_16x16x32_bf16(a0, bfr, acc2[0][nf], 0, 0, 0);
      acc2[1][nf] = __builtin_amdgcn_mfma_f32_16x16x32_bf16(a1, bfr, acc2[1][nf], 0, 0, 0);
    }
  }
  __syncthreads(); // done reading sA/sW; reuse for stats reduce

  float* sred = (float*)sA;          // [4][128]
  float* qred = (float*)(sA + 2048); // [4][128]
  u16* zp = (u16*)z;
  #pragma unroll
  for (int nf = 0; nf < 8; ++nf) {
    const int col = nf * 16 + lrow;
    const float bb = b2[col];
    float s = 0.f, q = 0.f;
    #pragma unroll
    for (int mf = 0; mf < 2; ++mf) {
      #pragma unroll
      for (int j = 0; j < 4; ++j) {
        int grow = m0 + wm + mf * 16 + crow + j;
        if (grow < Nn) {
          float v = acc2[mf][nf][j] + bb;
          zp[(size_t)grow * Hd + col] = f2bf(v);
          s += v; q += v * v;
        }
      }
    }
    s += __shfl_xor(s, 16, 64); s += __shfl_xor(s, 32, 64);
    q += __shfl_xor(q, 16, 64); q += __shfl_xor(q, 32, 64);
    if (lane < 16) { sred[wave * 128 + col] = s; qred[wave * 128 + col] = q; }
  }
  __syncthreads();
  if (tid < 128) {
    float a = sred[tid] + sred[128 + tid] + sred[256 + tid] + sred[384 + tid];
    pstats[(size_t)blockIdx.x * 256 + tid] = a;
  } else {
    int c = tid - 128;
    float a = qred[c] + qred[128 + c] + qred[256 + c] + qred[384 + c];
    pstats[(size_t)blockIdx.x * 256 + tid] = a;
  }
}

// ---- fused stats reduce + BN param: one block per feature ----
__global__ __launch_bounds__(256) void stats_bn_kernel(const float* __restrict__ pstats,
                                                       const float* __restrict__ gammas,
                                                       const float* __restrict__ betas,
                                                       int layer, float* __restrict__ ss) {
  __shared__ float reds[256];
  __shared__ float redq[256];
  int f = blockIdx.x; // 0..127
  int t = threadIdx.x;
  float s = 0.f, q = 0.f;
  for (int i = t; i < NBLK; i += 256) {
    s += pstats[(size_t)i * 256 + f];
    q += pstats[(size_t)i * 256 + 128 + f];
  }
  reds[t] = s; redq[t] = q;
  __syncthreads();
  for (int o = 128; o > 0; o >>= 1) {
    if (t < o) { reds[t] += reds[t + o]; redq[t] += redq[t + o]; }
    __syncthreads();
  }
  if (t == 0) {
    const float invn = 1.0f / (float)Nn;
    float mu = reds[0] * invn;
    float var = redq[0] * invn - mu * mu;
    float sc = gammas[layer * Hd + f] * rsqrtf(var + 1e-5f);
    ss[f] = sc;
    ss[Hd + f] = betas[layer * Hd + f] - mu * sc;
  }
}

// ---- one pooling kernel for all 5 sources, precomputed graph bounds, unroll-4 ILP ----
__global__ __launch_bounds__(128) void pool_all_kernel(const __hip_bfloat16* __restrict__ xb,
                                                       const __hip_bfloat16* __restrict__ z0,
                                                       const __hip_bfloat16* __restrict__ z1,
                                                       const __hip_bfloat16* __restrict__ z2,
                                                       const __hip_bfloat16* __restrict__ z3,
                                                       const float* __restrict__ ssbuf,
                                                       const int* __restrict__ gb,
                                                       float* __restrict__ emb) {
  const int b = blockIdx.x;
  const int s = b / (Gg * PSPLIT);
  const int rem = b % (Gg * PSPLIT);
  const int g = rem / PSPLIT, sp = rem % PSPLIT;
  const __hip_bfloat16* zsrc = (s == 0) ? xb : (s == 1) ? z0 : (s == 2) ? z1 : (s == 3) ? z2 : z3;
  const float* ss = ssbuf + (size_t)s * 256;
  const float negLim = (s == 0) ? -3.4e38f : 0.f;
  const int colOff = s * Hd;
  const int c2 = (threadIdx.x & 63) * 2;
  const int rh = threadIdx.x >> 6;
  const float sc0 = ss[c2], sh0 = ss[Hd + c2];
  const float sc1 = ss[c2 + 1], sh1 = ss[Hd + c2 + 1];
  const int lo = gb[g], hi = gb[g + 1];
  const int len = hi - lo;
  if (len <= 0) return;
  const int chunk = (len + PSPLIT - 1) / PSPLIT;
  const int rs = lo + sp * chunk;
  const int re = min(rs + chunk, hi);
  if (rs >= re) return;
  const u16* zp = (const u16*)zsrc;
  float a0 = 0.f, a1 = 0.f, b0 = 0.f, b1v = 0.f, d0 = 0.f, d1 = 0.f, e0 = 0.f, e1 = 0.f;
  int i = rs + rh;
  for (; i + 6 < re; i += 8) {
    u32 v0 = *(const u32*)(zp + (size_t)i * Hd + c2);
    u32 v1 = *(const u32*)(zp + (size_t)(i + 2) * Hd + c2);
    u32 v2 = *(const u32*)(zp + (size_t)(i + 4) * Hd + c2);
    u32 v3 = *(const u32*)(zp + (size_t)(i + 6) * Hd + c2);
    a0 += fmaxf(fmaf(bf2f(v0 & 0xffffu), sc0, sh0), negLim);
    a1 += fmaxf(fmaf(bf2f(v0 >> 16), sc1, sh1), negLim);
    b0 += fmaxf(fmaf(bf2f(v1 & 0xffffu), sc0, sh0), negLim);
    b1v += fmaxf(fmaf(bf2f(v1 >> 16), sc1, sh1), negLim);
    d0 += fmaxf(fmaf(bf2f(v2 & 0xffffu), sc0, sh0), negLim);
    d1 += fmaxf(fmaf(bf2f(v2 >> 16), sc1, sh1), negLim);
    e0 += fmaxf(fmaf(bf2f(v3 & 0xffffu), sc0, sh0), negLim);
    e1 += fmaxf(fmaf(bf2f(v3 >> 16), sc1, sh1), negLim);
  }
  for (; i < re; i += 2) {
    u32 v = *(const u32*)(zp + (size_t)i * Hd + c2);
    a0 += fmaxf(fmaf(bf2f(v & 0xffffu), sc0, sh0), negLim);
    a1 += fmaxf(fmaf(bf2f(v >> 16), sc1, sh1), negLim);
  }
  a0 += b0 + d0 + e0;
  a1 += b1v + d1 + e1;
  atomicAdd(&emb[g * Din + colOff + c2], a0);
  atomicAdd(&emb[g * Din + colOff + c2 + 1], a1);
}

// ---- output head: out = emb @ Wout + bout ----
__global__ __launch_bounds__(64) void out_kernel(const float* __restrict__ emb, const float* __restrict__ Wout,
                                                 const float* __restrict__ bout, float* __restrict__ out) {
  int g = blockIdx.x;
  int lane = threadIdx.x;
  float acc[Oo];
  #pragma unroll
  for (int o = 0; o < Oo; ++o) acc[o] = 0.f;
  for (int d = lane; d < Din; d += 64) {
    float ev = emb[g * Din + d];
    #pragma unroll
    for (int o = 0; o < Oo; ++o) acc[o] += ev * Wout[d * Oo + o];
  }
  #pragma unroll
  for (int off = 32; off > 0; off >>= 1) {
    #pragma unroll
    for (int o = 0; o < Oo; ++o) acc[o] += __shfl_down(acc[o], off, 64);
  }
  if (lane == 0) {
    #pragma unroll
    for (int o = 0; o < Oo; ++o) out[g * Oo + o] = acc[o] + bout[o];
  }
}

extern "C" void kernel_launch(void* const* d_in, const int* in_sizes, int n_in,
                              void* d_out, int out_size, void* d_ws, size_t ws_size,
                              hipStream_t stream) {
  (void)in_sizes; (void)n_in; (void)out_size;
  const float* x = (const float*)d_in[0];
  const int* ei = (const int*)d_in[1];
  const int* src = ei;
  const int* dst = ei + Ee;
  const int* batch = (const int*)d_in[2];
  const float* W1s = (const float*)d_in[3];
  const float* b1s = (const float*)d_in[4];
  const float* W2s = (const float*)d_in[5];
  const float* b2s = (const float*)d_in[6];
  const float* eps = (const float*)d_in[7];
  const float* gammas = (const float*)d_in[8];
  const float* betas = (const float*)d_in[9];
  const float* Wout = (const float*)d_in[10];
  const float* bout = (const float*)d_in[11];
  float* out = (float*)d_out;

  unsigned char* ws = (unsigned char*)d_ws;
  size_t off = 0;
  auto alloc = [&](size_t bytes) -> void* {
    void* p = ws + off;
    off = (off + bytes + 255) & ~size_t(255);
    return p;
  };
  __hip_bfloat16* xb = (__hip_bfloat16*)alloc((size_t)Nn * Hd * 2);
  __hip_bfloat16* z[Ll];
  for (int l = 0; l < Ll; ++l) z[l] = (__hip_bfloat16*)alloc((size_t)Nn * Hd * 2);
  __hip_bfloat16* t = (__hip_bfloat16*)alloc((size_t)Nn * Hd * 2);
  int* indptr = (int*)alloc((size_t)(Nn + 1) * 4);  // readable pad after t (OOB tile rows)
  int* adj = (int*)alloc((size_t)Ee * 4);
  u32* buckets = (u32*)alloc((size_t)NB * BCAP * 4);
  int* gptr = (int*)alloc((size_t)NB * 4);
  int* bmeta = (int*)alloc((size_t)2 * NB * 4);
  int* gb = (int*)alloc((size_t)(Gg + 1) * 4);
  float* emb = (float*)alloc((size_t)Gg * Din * 4);
  float* pstats = (float*)alloc((size_t)NBLK * 256 * 4);
  float* ssbuf = (float*)alloc((size_t)(Ll + 1) * 256 * 4);
  __hip_bfloat16* wt = (__hip_bfloat16*)alloc((size_t)Ll * 2 * Hd * Hd * 2);
  if (off > ws_size) return; // workspace too small -> leave output poisoned (visible failure)

  hipMemsetAsync(emb, 0, (size_t)Gg * Din * 4, stream);

  prep_kernel<<<XCVT_BLKS + WPREP_BLKS + 1, 256, 0, stream>>>(x, xb, W1s, W2s, wt, ssbuf, gptr,
                                                              batch, gb);

  // bucketed CSR build
  binA_kernel<<<NBATCH, 256, 0, stream>>>(src, dst, gptr, buckets);
  bucketscan_kernel<<<1, NB, 0, stream>>>(gptr, bmeta, indptr);
  place_kernel<<<NB, 512, 0, stream>>>(buckets, bmeta, indptr, adj);

  const __hip_bfloat16* zprev = xb;
  for (int l = 0; l < Ll; ++l) {
    float negLim = (l == 0) ? -3.4e38f : 0.f;
    agg_kernel<<<AGG_BLKS, 256, 0, stream>>>(zprev, indptr, adj, ssbuf + (size_t)l * 256,
                                             eps, l, negLim, t);
    mlp_kernel<<<NBLK, 256, 0, stream>>>(
        t, wt + (size_t)l * 2 * Hd * Hd, wt + (size_t)l * 2 * Hd * Hd + Hd * Hd,
        b1s + l * Hd, b2s + l * Hd, z[l], pstats);
    stats_bn_kernel<<<128, 256, 0, stream>>>(pstats, gammas, betas, l, ssbuf + (size_t)(l + 1) * 256);
    zprev = z[l];
  }

  pool_all_kernel<<<5 * Gg * PSPLIT, 128, 0, stream>>>(xb, z[0], z[1], z[2], z[3],
                                                       ssbuf, gb, emb);

  out_kernel<<<Gg, 64, 0, stream>>>(emb, Wout, bout, out);
}